// Round 2
// baseline (740.953 us; speedup 1.0000x reference)
//
#include <hip/hip_runtime.h>
#include <stdint.h>

#define DEVI __device__ __forceinline__

typedef __bf16 bf16x8 __attribute__((ext_vector_type(8)));
typedef float f32x4 __attribute__((ext_vector_type(4)));

// Problem constants
static constexpr int CB = 16;      // batch
static constexpr int CL = 512;     // seq len
static constexpr int CD = 1024;    // model dim
static constexpr int CH = 16;      // heads
static constexpr int CDK = 64;     // head dim
static constexpr int CBH = CB * CH;        // 256
static constexpr int CM = CB * CL;         // 8192 rows

DEVI uint16_t f2bf(float f) {
  union { float f; uint32_t u; } a; a.f = f;
  uint32_t r = a.u + 0x7fffu + ((a.u >> 16) & 1u);  // RNE
  return (uint16_t)(r >> 16);
}

DEVI f32x4 mfma16(bf16x8 a, bf16x8 b, f32x4 c) {
  return __builtin_amdgcn_mfma_f32_16x16x32_bf16(a, b, c, 0, 0, 0);
}

DEVI void gl_lds16(const void* g, void* l) {
  __builtin_amdgcn_global_load_lds(
      (const __attribute__((address_space(1))) void*)g,
      (__attribute__((address_space(3))) void*)l, 16, 0, 0);
}

DEVI bf16x8 ld_bf8(const uint16_t* p) { return *(const bf16x8*)p; }

// ---------------- fp32 -> bf16 cast ----------------
__global__ __launch_bounds__(256) void cvt_kernel(const float* __restrict__ in,
                                                  uint16_t* __restrict__ out, int n4) {
  int i = blockIdx.x * blockDim.x + threadIdx.x;
  int stride = gridDim.x * blockDim.x;
  for (; i < n4; i += stride) {
    float4 v = ((const float4*)in)[i];
    ushort4 o;
    o.x = f2bf(v.x); o.y = f2bf(v.y); o.z = f2bf(v.z); o.w = f2bf(v.w);
    ((ushort4*)out)[i] = o;
  }
}

// ---------------- 1024x1024 transpose + cast (weights -> B^T layout) ----------------
__global__ __launch_bounds__(256) void wtrans_kernel(const float* __restrict__ in,
                                                     uint16_t* __restrict__ out) {
  __shared__ float tile[32][33];
  int bx = blockIdx.x * 32, by = blockIdx.y * 32;
  int tx = threadIdx.x, ty = threadIdx.y;  // block (32,8)
#pragma unroll
  for (int i = 0; i < 32; i += 8)
    tile[ty + i][tx] = in[(size_t)(by + ty + i) * 1024 + bx + tx];
  __syncthreads();
#pragma unroll
  for (int i = 0; i < 32; i += 8)
    out[(size_t)(bx + ty + i) * 1024 + by + tx] = f2bf(tile[tx][ty + i]);
}

// ---------------- bias gather: bias[h][i][j] = rel_table[rel_index[i][j]][h] ----------------
__global__ __launch_bounds__(512) void bias_kernel(const float* __restrict__ rel_table,
                                                   const int* __restrict__ rel_index,
                                                   float* __restrict__ bias) {
  int j = threadIdx.x;      // 0..511 (use <511)
  int i = blockIdx.x;       // 0..510
  int h = blockIdx.y;       // 0..15
  if (j < 511)
    bias[((size_t)h * 511 + i) * 511 + j] =
        rel_table[(size_t)rel_index[i * 512 + j] * 16 + h];
}

// ---------------- GEMM mainloop: C = A(MxK) * Bt(NxK)^T, 128x128 tile, BK=32 ----------------
DEVI void gemm_core(const uint16_t* __restrict__ A, const uint16_t* __restrict__ Bt,
                    int K, uint16_t* As, uint16_t* Bs, f32x4 (&acc)[4][4]) {
  const int tid = threadIdx.x;
  const int srow = tid >> 2;           // 0..63
  const int scol = (tid & 3) * 8;      // 0,8,16,24
  const uint16_t* Ag = A + (size_t)srow * K + scol;
  const uint16_t* Bg = Bt + (size_t)srow * K + scol;
  uint16_t* Asl = As + srow * 32 + scol;   // byte off = tid*16 (wave base + lane*16)
  uint16_t* Bsl = Bs + srow * 32 + scol;
  const int fr = tid & 15;
  const int fk = ((tid >> 4) & 3) * 8;
  const int w = tid >> 6;
  const int wm = (w >> 1) * 64, wn = (w & 1) * 64;
  for (int k0 = 0; k0 < K; k0 += 32) {
    gl_lds16(Ag + k0, Asl);
    gl_lds16(Ag + (size_t)64 * K + k0, Asl + 64 * 32);
    gl_lds16(Bg + k0, Bsl);
    gl_lds16(Bg + (size_t)64 * K + k0, Bsl + 64 * 32);
    asm volatile("s_waitcnt vmcnt(0)" ::: "memory");
    __syncthreads();
    bf16x8 af[4], bfr[4];
#pragma unroll
    for (int t = 0; t < 4; ++t) af[t] = ld_bf8(As + (wm + t * 16 + fr) * 32 + fk);
#pragma unroll
    for (int t = 0; t < 4; ++t) bfr[t] = ld_bf8(Bs + (wn + t * 16 + fr) * 32 + fk);
#pragma unroll
    for (int mt = 0; mt < 4; ++mt)
#pragma unroll
      for (int nt = 0; nt < 4; ++nt)
        acc[mt][nt] = mfma16(af[mt], bfr[nt], acc[mt][nt]);
    __syncthreads();
  }
}

// ---------------- projection GEMM (z = 0:q, 1:k, 2:v); out (BH, L, 64) bf16 ----------------
__global__ __launch_bounds__(256) void proj_kernel(
    const uint16_t* __restrict__ qb, const uint16_t* __restrict__ kb,
    const uint16_t* __restrict__ vb, const uint16_t* __restrict__ wq,
    const uint16_t* __restrict__ wk, const uint16_t* __restrict__ wv,
    uint16_t* __restrict__ qh, uint16_t* __restrict__ kh, uint16_t* __restrict__ vh) {
  __shared__ uint16_t As[128 * 32], Bs[128 * 32];
  const int z = blockIdx.z;
  const uint16_t* A = (z == 0) ? qb : ((z == 1) ? kb : vb);
  const uint16_t* Bt = (z == 0) ? wq : ((z == 1) ? wk : wv);
  uint16_t* out = (z == 0) ? qh : ((z == 1) ? kh : vh);
  const float scale = (z == 0) ? 0.125f : 1.0f;  // 1/sqrt(DK) on Q only
  const int m0 = blockIdx.y * 128, n0 = blockIdx.x * 128;
  f32x4 acc[4][4] = {};
  gemm_core(A + (size_t)m0 * CD, Bt + (size_t)n0 * CD, CD, As, Bs, acc);
  const int tid = threadIdx.x;
  const int w = tid >> 6, fr = tid & 15, fg = (tid >> 4) & 3;
  const int wm = (w >> 1) * 64, wn = (w & 1) * 64;
#pragma unroll
  for (int mt = 0; mt < 4; ++mt)
#pragma unroll
    for (int nt = 0; nt < 4; ++nt)
#pragma unroll
      for (int r = 0; r < 4; ++r) {
        int gm = m0 + wm + mt * 16 + fg * 4 + r;   // b*512 + l
        int gn = n0 + wn + nt * 16 + fr;           // h*64 + d
        int b = gm >> 9, l = gm & 511, h = gn >> 6, d = gn & 63;
        out[(((size_t)(b * 16 + h) << 9) + l) * 64 + d] = f2bf(acc[mt][nt][r] * scale);
      }
}

// ---------------- FC GEMM + residual; fp32 out ----------------
__global__ __launch_bounds__(256) void fc_kernel(const uint16_t* __restrict__ A,
                                                 const uint16_t* __restrict__ Wt,
                                                 const float* __restrict__ resid,
                                                 float* __restrict__ out) {
  __shared__ uint16_t As[128 * 32], Bs[128 * 32];
  const int m0 = blockIdx.y * 128, n0 = blockIdx.x * 128;
  f32x4 acc[4][4] = {};
  gemm_core(A + (size_t)m0 * CD, Wt + (size_t)n0 * CD, CD, As, Bs, acc);
  const int tid = threadIdx.x;
  const int w = tid >> 6, fr = tid & 15, fg = (tid >> 4) & 3;
  const int wm = (w >> 1) * 64, wn = (w & 1) * 64;
#pragma unroll
  for (int mt = 0; mt < 4; ++mt)
#pragma unroll
    for (int nt = 0; nt < 4; ++nt)
#pragma unroll
      for (int r = 0; r < 4; ++r) {
        int gm = m0 + wm + mt * 16 + fg * 4 + r;
        int gn = n0 + wn + nt * 16 + fr;
        size_t idx = (size_t)gm * CD + gn;
        out[idx] = acc[mt][nt][r] + resid[idx];
      }
}

// ---------------- fused attention: scores + bias + softmax + PV ----------------
// grid (L/64, B*H), block 256 (4 waves, each wave owns 16 q rows)
__global__ __launch_bounds__(256) void attn_kernel(
    const uint16_t* __restrict__ qh, const uint16_t* __restrict__ kh,
    const uint16_t* __restrict__ vh, const float* __restrict__ bias,
    uint16_t* __restrict__ out) {
  __shared__ uint16_t P[4][16 * 512];   // per-wave P, XOR-swizzled cols
  __shared__ uint16_t VT[64 * 512];     // V^T [d][l], XOR-swizzled cols
  const int bh = blockIdx.y, h = bh & 15, b = bh >> 4;
  const int q0 = blockIdx.x * 64;
  const int tid = threadIdx.x, lane = tid & 63, w = tid >> 6;
  const int fr = lane & 15, fg = lane >> 4;
  const size_t base = (size_t)bh * CL * 64;
  const uint16_t* Kp = kh + base;
  const uint16_t* Vp = vh + base;
  const uint16_t* Qp = qh + base;

  // --- stage V^T into LDS (swizzle: col-block ^= row&7) ---
#pragma unroll 4
  for (int it = 0; it < 128; ++it) {
    int l = it * 4 + w;
    uint16_t val = Vp[(size_t)l * 64 + lane];
    VT[lane * 512 + (((l >> 3) ^ (lane & 7)) << 3) + (l & 7)] = val;
  }

  // --- scores S = (Q/8) K^T + bias ---
  const int qw = q0 + w * 16;
  bf16x8 qa0 = ld_bf8(Qp + (size_t)(qw + fr) * 64 + fg * 8);
  bf16x8 qa1 = ld_bf8(Qp + (size_t)(qw + fr) * 64 + 32 + fg * 8);
  float S[32][4];
#pragma unroll
  for (int nt = 0; nt < 32; ++nt) {
    bf16x8 kb0 = ld_bf8(Kp + (size_t)(nt * 16 + fr) * 64 + fg * 8);
    bf16x8 kb1 = ld_bf8(Kp + (size_t)(nt * 16 + fr) * 64 + 32 + fg * 8);
    f32x4 c = {};
    c = mfma16(qa0, kb0, c);
    c = mfma16(qa1, kb1, c);
    int kcol = nt * 16 + fr;
#pragma unroll
    for (int r = 0; r < 4; ++r) {
      int qrow = qw + fg * 4 + r;
      float val = c[r];
      if (qrow >= 1 && kcol >= 1)
        val += bias[((size_t)h * 511 + (qrow - 1)) * 511 + (kcol - 1)];
      S[nt][r] = val;
    }
  }

  // --- softmax over 512 cols: reduce over 16-lane groups (rows 4g..4g+3 in regs) ---
#pragma unroll
  for (int r = 0; r < 4; ++r) {
    float m = -1e30f;
#pragma unroll
    for (int nt = 0; nt < 32; ++nt) m = fmaxf(m, S[nt][r]);
#pragma unroll
    for (int off = 1; off < 16; off <<= 1) m = fmaxf(m, __shfl_xor(m, off));
    float s = 0.f;
#pragma unroll
    for (int nt = 0; nt < 32; ++nt) { float e = __expf(S[nt][r] - m); S[nt][r] = e; s += e; }
#pragma unroll
    for (int off = 1; off < 16; off <<= 1) s += __shfl_xor(s, off);
    float inv = 1.0f / s;
#pragma unroll
    for (int nt = 0; nt < 32; ++nt) S[nt][r] *= inv;
  }

  // --- P -> LDS (bf16, swizzled) ---
  uint16_t* Pw = P[w];
#pragma unroll
  for (int nt = 0; nt < 32; ++nt) {
    int cb = nt * 2 + (fr >> 3);   // col block
    int co = fr & 7;               // col offset in block
#pragma unroll
    for (int r = 0; r < 4; ++r) {
      int row = fg * 4 + r;
      Pw[row * 512 + ((cb ^ (row & 7)) << 3) + co] = f2bf(S[nt][r]);
    }
  }
  __syncthreads();  // VT + P visible to all lanes

  // --- PV: O[16x64] = P[16x512] * V[512x64] ---
  f32x4 o[4] = {};
#pragma unroll
  for (int ks = 0; ks < 16; ++ks) {
    bf16x8 pa = ld_bf8(Pw + fr * 512 + (((ks * 4 + fg) ^ (fr & 7)) << 3));
#pragma unroll
    for (int n2 = 0; n2 < 4; ++n2) {
      int vrow = n2 * 16 + fr;
      bf16x8 vb = ld_bf8(VT + vrow * 512 + (((ks * 4 + fg) ^ (vrow & 7)) << 3));
      o[n2] = mfma16(pa, vb, o[n2]);
    }
  }

  // --- write out (B, L, H*64) bf16 ---
#pragma unroll
  for (int n2 = 0; n2 < 4; ++n2)
#pragma unroll
    for (int r = 0; r < 4; ++r) {
      int q = qw + fg * 4 + r;
      int d = n2 * 16 + fr;
      out[(size_t)(b * CL + q) * CD + h * 64 + d] = f2bf(o[n2][r]);
    }
}

// ---------------- LayerNorm over D=1024, one block per row ----------------
__global__ __launch_bounds__(256) void ln_kernel(const float* __restrict__ x,
                                                 const float* __restrict__ gamma,
                                                 const float* __restrict__ beta,
                                                 float* __restrict__ out) {
  const int row = blockIdx.x;
  const int tid = threadIdx.x;
  const float4 v = ((const float4*)(x + (size_t)row * 1024))[tid];
  float s = v.x + v.y + v.z + v.w;
  float ss = v.x * v.x + v.y * v.y + v.z * v.z + v.w * v.w;
#pragma unroll
  for (int off = 1; off < 64; off <<= 1) {
    s += __shfl_xor(s, off);
    ss += __shfl_xor(ss, off);
  }
  __shared__ float ps[4], pss[4];
  const int w = tid >> 6, lane = tid & 63;
  if (lane == 0) { ps[w] = s; pss[w] = ss; }
  __syncthreads();
  s = ps[0] + ps[1] + ps[2] + ps[3];
  ss = pss[0] + pss[1] + pss[2] + pss[3];
  float mu = s * (1.0f / 1024.0f);
  float var = ss * (1.0f / 1024.0f) - mu * mu;
  float rs = rsqrtf(var + 1e-6f);
  const float4 g = ((const float4*)gamma)[tid];
  const float4 be = ((const float4*)beta)[tid];
  float4 o;
  o.x = (v.x - mu) * rs * g.x + be.x;
  o.y = (v.y - mu) * rs * g.y + be.y;
  o.z = (v.z - mu) * rs * g.z + be.z;
  o.w = (v.w - mu) * rs * g.w + be.w;
  ((float4*)(out + (size_t)row * 1024))[tid] = o;
}

extern "C" void kernel_launch(void* const* d_in, const int* in_sizes, int n_in,
                              void* d_out, int out_size, void* d_ws, size_t ws_size,
                              hipStream_t stream) {
  (void)in_sizes; (void)n_in; (void)out_size; (void)ws_size;
  const float* q = (const float*)d_in[0];
  const float* k = (const float*)d_in[1];
  const float* v = (const float*)d_in[2];
  const float* w_q = (const float*)d_in[3];
  const float* w_k = (const float*)d_in[4];
  const float* w_v = (const float*)d_in[5];
  const float* w_fc = (const float*)d_in[6];
  const float* rel_table = (const float*)d_in[7];
  const int* rel_index = (const int*)d_in[8];
  const float* ln_g = (const float*)d_in[9];
  const float* ln_b = (const float*)d_in[10];
  float* out = (float*)d_out;

  uint8_t* ws = (uint8_t*)d_ws;
  size_t off = 0;
  auto carve = [&](size_t bytes) {
    uint8_t* p = ws + off;
    off += (bytes + 255) & ~(size_t)255;
    return p;
  };
  uint16_t* wqt = (uint16_t*)carve((size_t)CD * CD * 2);
  uint16_t* wkt = (uint16_t*)carve((size_t)CD * CD * 2);
  uint16_t* wvt = (uint16_t*)carve((size_t)CD * CD * 2);
  uint16_t* wft = (uint16_t*)carve((size_t)CD * CD * 2);
  uint16_t* qb = (uint16_t*)carve((size_t)CM * CD * 2);  // reused as fc_out (with kb)
  uint16_t* kb = (uint16_t*)carve((size_t)CM * CD * 2);
  uint16_t* vb = (uint16_t*)carve((size_t)CM * CD * 2);  // reused as attn_out
  uint16_t* qhp = (uint16_t*)carve((size_t)CBH * CL * 64 * 2);
  uint16_t* khp = (uint16_t*)carve((size_t)CBH * CL * 64 * 2);
  uint16_t* vhp = (uint16_t*)carve((size_t)CBH * CL * 64 * 2);
  float* biasp = (float*)carve((size_t)CH * 511 * 511 * 4);
  uint16_t* attn_out = vb;        // vb dead after proj consumes it
  float* fc_out = (float*)qb;     // qb+kb dead after proj (32MB contiguous)

  const int n4 = CM * CD / 4;
  cvt_kernel<<<2048, 256, 0, stream>>>(q, qb, n4);
  cvt_kernel<<<2048, 256, 0, stream>>>(k, kb, n4);
  cvt_kernel<<<2048, 256, 0, stream>>>(v, vb, n4);
  dim3 tb(32, 8);
  wtrans_kernel<<<dim3(32, 32), tb, 0, stream>>>(w_q, wqt);
  wtrans_kernel<<<dim3(32, 32), tb, 0, stream>>>(w_k, wkt);
  wtrans_kernel<<<dim3(32, 32), tb, 0, stream>>>(w_v, wvt);
  wtrans_kernel<<<dim3(32, 32), tb, 0, stream>>>(w_fc, wft);
  bias_kernel<<<dim3(511, 16), 512, 0, stream>>>(rel_table, rel_index, biasp);

  proj_kernel<<<dim3(CD / 128, CM / 128, 3), 256, 0, stream>>>(
      qb, kb, vb, wqt, wkt, wvt, qhp, khp, vhp);

  attn_kernel<<<dim3(CL / 64, CBH), 256, 0, stream>>>(qhp, khp, vhp, biasp, attn_out);

  fc_kernel<<<dim3(CD / 128, CM / 128), 256, 0, stream>>>(attn_out, wft, q, fc_out);

  ln_kernel<<<CM, 256, 0, stream>>>(fc_out, ln_g, ln_b, out);
}

// Round 4
// 394.686 us; speedup vs baseline: 1.8773x; 1.8773x over previous
//
#include <hip/hip_runtime.h>
#include <stdint.h>

#define DEVI __device__ __forceinline__

typedef __bf16 bf16x8 __attribute__((ext_vector_type(8)));
typedef float f32x4 __attribute__((ext_vector_type(4)));

// Problem constants
static constexpr int CB = 16;      // batch
static constexpr int CL = 512;     // seq len
static constexpr int CD = 1024;    // model dim
static constexpr int CH = 16;      // heads
static constexpr int CBH = CB * CH;        // 256
static constexpr int CM = CB * CL;         // 8192 rows
static constexpr int TPAD = 3392;          // rel_table slice padded (3375 -> /16)

DEVI uint16_t f2bf(float f) {
  union { float f; uint32_t u; } a; a.f = f;
  uint32_t r = a.u + 0x7fffu + ((a.u >> 16) & 1u);  // RNE
  return (uint16_t)(r >> 16);
}

DEVI f32x4 mfma16(bf16x8 a, bf16x8 b, f32x4 c) {
  return __builtin_amdgcn_mfma_f32_16x16x32_bf16(a, b, c, 0, 0, 0);
}

DEVI void gl_lds16(const void* g, void* l) {
  __builtin_amdgcn_global_load_lds(
      (const __attribute__((address_space(1))) void*)g,
      (__attribute__((address_space(3))) void*)l, 16, 0, 0);
}

DEVI bf16x8 ld_bf8(const uint16_t* p) { return *(const bf16x8*)p; }

// ---------------- fp32 -> bf16 cast ----------------
__global__ __launch_bounds__(256) void cvt_kernel(const float* __restrict__ in,
                                                  uint16_t* __restrict__ out, int n4) {
  int i = blockIdx.x * blockDim.x + threadIdx.x;
  int stride = gridDim.x * blockDim.x;
  for (; i < n4; i += stride) {
    float4 v = ((const float4*)in)[i];
    ushort4 o;
    o.x = f2bf(v.x); o.y = f2bf(v.y); o.z = f2bf(v.z); o.w = f2bf(v.w);
    ((ushort4*)out)[i] = o;
  }
}

// ---------------- 1024x1024 transpose + cast (weights -> B^T layout) ----------------
__global__ __launch_bounds__(256) void wtrans_kernel(const float* __restrict__ in,
                                                     uint16_t* __restrict__ out) {
  __shared__ float tile[32][33];
  int bx = blockIdx.x * 32, by = blockIdx.y * 32;
  int tx = threadIdx.x, ty = threadIdx.y;  // block (32,8)
#pragma unroll
  for (int i = 0; i < 32; i += 8)
    tile[ty + i][tx] = in[(size_t)(by + ty + i) * 1024 + bx + tx];
  __syncthreads();
#pragma unroll
  for (int i = 0; i < 32; i += 8)
    out[(size_t)(bx + ty + i) * 1024 + by + tx] = f2bf(tile[tx][ty + i]);
}

// ---------------- rel_table (3375,16) -> padded transposed (16, 3392) ----------------
__global__ __launch_bounds__(256) void ttrans_kernel(const float* __restrict__ rt,
                                                     float* __restrict__ rtT) {
  int h = blockIdx.x;
  for (int i = threadIdx.x; i < 3375; i += 256)
    rtT[(size_t)h * TPAD + i] = rt[(size_t)i * 16 + h];
}

// ---------------- V heads (bh,512,64) -> (bh,64,512) bf16 ----------------
__global__ __launch_bounds__(256) void vtrans_kernel(const uint16_t* __restrict__ in,
                                                     uint16_t* __restrict__ out) {
  __shared__ uint t[64][33];
  const int bh = blockIdx.x, l0 = blockIdx.y * 64;
  const int tid = threadIdx.x, tx = tid & 31, ty = tid >> 5;
  const uint* src = (const uint*)(in + ((size_t)bh * 512 + l0) * 64);
#pragma unroll
  for (int i = 0; i < 8; ++i)
    t[ty * 8 + i][tx] = src[(ty * 8 + i) * 32 + tx];
  __syncthreads();
#pragma unroll
  for (int i = 0; i < 8; ++i) {
    int d = ty + i * 8;
    uint w0 = t[tx * 2][d >> 1], w1 = t[tx * 2 + 1][d >> 1];
    uint v0 = (d & 1) ? (w0 >> 16) : (w0 & 0xffffu);
    uint v1 = (d & 1) ? (w1 >> 16) : (w1 & 0xffffu);
    ((uint*)(out + ((size_t)(bh * 64 + d) * 512 + l0)))[tx] = v0 | (v1 << 16);
  }
}

// ---------------- GEMM mainloop: C = A(MxK) * Bt(NxK)^T, 128x128 tile, BK=32 ----------------
DEVI void gemm_core(const uint16_t* __restrict__ A, const uint16_t* __restrict__ Bt,
                    int K, uint16_t* As, uint16_t* Bs, f32x4 (&acc)[4][4]) {
  const int tid = threadIdx.x;
  const int srow = tid >> 2;           // 0..63
  const int scol = (tid & 3) * 8;      // 0,8,16,24
  const uint16_t* Ag = A + (size_t)srow * K + scol;
  const uint16_t* Bg = Bt + (size_t)srow * K + scol;
  uint16_t* Asl = As + srow * 32 + scol;   // byte off = tid*16 (wave base + lane*16)
  uint16_t* Bsl = Bs + srow * 32 + scol;
  const int fr = tid & 15;
  const int fk = ((tid >> 4) & 3) * 8;
  const int w = tid >> 6;
  const int wm = (w >> 1) * 64, wn = (w & 1) * 64;
  for (int k0 = 0; k0 < K; k0 += 32) {
    gl_lds16(Ag + k0, Asl);
    gl_lds16(Ag + (size_t)64 * K + k0, Asl + 64 * 32);
    gl_lds16(Bg + k0, Bsl);
    gl_lds16(Bg + (size_t)64 * K + k0, Bsl + 64 * 32);
    asm volatile("s_waitcnt vmcnt(0)" ::: "memory");
    __syncthreads();
    bf16x8 af[4], bfr[4];
#pragma unroll
    for (int t = 0; t < 4; ++t) af[t] = ld_bf8(As + (wm + t * 16 + fr) * 32 + fk);
#pragma unroll
    for (int t = 0; t < 4; ++t) bfr[t] = ld_bf8(Bs + (wn + t * 16 + fr) * 32 + fk);
#pragma unroll
    for (int mt = 0; mt < 4; ++mt)
#pragma unroll
      for (int nt = 0; nt < 4; ++nt)
        acc[mt][nt] = mfma16(af[mt], bfr[nt], acc[mt][nt]);
    __syncthreads();
  }
}

// ---------------- projection GEMM (z = 0:q, 1:k, 2:v); out (BH, L, 64) bf16 ----------------
__global__ __launch_bounds__(256) void proj_kernel(
    const uint16_t* __restrict__ qb, const uint16_t* __restrict__ kb,
    const uint16_t* __restrict__ vb, const uint16_t* __restrict__ wq,
    const uint16_t* __restrict__ wk, const uint16_t* __restrict__ wv,
    uint16_t* __restrict__ qh, uint16_t* __restrict__ kh, uint16_t* __restrict__ vh) {
  __shared__ uint16_t As[128 * 32], Bs[128 * 32];
  const int z = blockIdx.z;
  const uint16_t* A = (z == 0) ? qb : ((z == 1) ? kb : vb);
  const uint16_t* Bt = (z == 0) ? wq : ((z == 1) ? wk : wv);
  uint16_t* out = (z == 0) ? qh : ((z == 1) ? kh : vh);
  const float scale = (z == 0) ? 0.125f : 1.0f;  // 1/sqrt(DK) on Q only
  const int m0 = blockIdx.y * 128, n0 = blockIdx.x * 128;
  f32x4 acc[4][4] = {};
  gemm_core(A + (size_t)m0 * CD, Bt + (size_t)n0 * CD, CD, As, Bs, acc);
  const int tid = threadIdx.x;
  const int w = tid >> 6, fr = tid & 15, fg = (tid >> 4) & 3;
  const int wm = (w >> 1) * 64, wn = (w & 1) * 64;
#pragma unroll
  for (int mt = 0; mt < 4; ++mt)
#pragma unroll
    for (int nt = 0; nt < 4; ++nt)
#pragma unroll
      for (int r = 0; r < 4; ++r) {
        int gm = m0 + wm + mt * 16 + fg * 4 + r;   // b*512 + l
        int gn = n0 + wn + nt * 16 + fr;           // h*64 + d
        int b = gm >> 9, l = gm & 511, h = gn >> 6, d = gn & 63;
        out[(((size_t)(b * 16 + h) << 9) + l) * 64 + d] = f2bf(acc[mt][nt][r] * scale);
      }
}

// ---------------- FC GEMM + residual; fp32 out ----------------
__global__ __launch_bounds__(256) void fc_kernel(const uint16_t* __restrict__ A,
                                                 const uint16_t* __restrict__ Wt,
                                                 const float* __restrict__ resid,
                                                 float* __restrict__ out) {
  __shared__ uint16_t As[128 * 32], Bs[128 * 32];
  const int m0 = blockIdx.y * 128, n0 = blockIdx.x * 128;
  f32x4 acc[4][4] = {};
  gemm_core(A + (size_t)m0 * CD, Wt + (size_t)n0 * CD, CD, As, Bs, acc);
  const int tid = threadIdx.x;
  const int w = tid >> 6, fr = tid & 15, fg = (tid >> 4) & 3;
  const int wm = (w >> 1) * 64, wn = (w & 1) * 64;
#pragma unroll
  for (int mt = 0; mt < 4; ++mt)
#pragma unroll
    for (int nt = 0; nt < 4; ++nt)
#pragma unroll
      for (int r = 0; r < 4; ++r) {
        int gm = m0 + wm + mt * 16 + fg * 4 + r;
        int gn = n0 + wn + nt * 16 + fr;
        size_t idx = (size_t)gm * CD + gn;
        out[idx] = acc[mt][nt][r] + resid[idx];
      }
}

// ---------------- fused attention: scores + inline rel-bias + softmax + PV ----------------
// grid (L/64, B*H), block 256 (4 waves, each wave owns 16 q rows)
// LDS: table slice 13.5KB + VT half 32KB + P half 32KB = 79KB -> 2 WG/CU
__global__ __launch_bounds__(256) void attn_kernel(
    const uint16_t* __restrict__ qh, const uint16_t* __restrict__ kh,
    const uint16_t* __restrict__ vt, const float* __restrict__ rtT,
    uint16_t* __restrict__ out) {
  __shared__ float Tb[TPAD];            // rel_table slice for this head
  __shared__ uint16_t VTh[64 * 256];    // V^T half [d][l'], XOR-swizzled 16B blocks
  __shared__ uint16_t Ph[4 * 16 * 256]; // per-wave P half, XOR-swizzled 16B blocks
  const int bh = blockIdx.y, h = bh & 15, b = bh >> 4;
  const int q0 = blockIdx.x * 64;
  const int tid = threadIdx.x, lane = tid & 63, w = tid >> 6;
  const int fr = lane & 15, fg = lane >> 4;
  const size_t base = (size_t)bh * CL * 64;
  const uint16_t* Kp = kh + base;
  const uint16_t* Qp = qh + base;
  const uint16_t* Vt = vt + base;       // (64, 512) layout

  // stage rel_table slice (coalesced float4)
  const float4* rt4 = (const float4*)(rtT + (size_t)h * TPAD);
#pragma unroll
  for (int t = tid; t < TPAD / 4; t += 256) ((float4*)Tb)[t] = rt4[t];

  // issue VT half-0 staging: linear LDS dest, inverse-swizzled global source (rule 21)
#pragma unroll
  for (int it = 0; it < 8; ++it) {
    int d = it * 8 + (tid >> 5);
    int cb = (tid & 31) ^ (d & 7);          // logical 16B col-block for this slot
    gl_lds16(Vt + (size_t)d * 512 + cb * 8, VTh + it * 2048 + tid * 8);
  }
  __syncthreads();  // Tb + VT half-0 ready

  // --- scores S = (Q/8) K^T + rel bias ---
  const int qw = q0 + w * 16;
  bf16x8 qa0 = ld_bf8(Qp + (size_t)(qw + fr) * 64 + fg * 8);
  bf16x8 qa1 = ld_bf8(Qp + (size_t)(qw + fr) * 64 + 32 + fg * 8);
  int PiA[4]; bool iok[4];
#pragma unroll
  for (int r = 0; r < 4; ++r) {
    int i = qw + fg * 4 + r - 1;
    iok[r] = (i >= 0);
    int ii = i < 0 ? 0 : i;
    PiA[r] = (ii >> 6) * 225 + ((ii >> 3) & 7) * 15 + (ii & 7) + 1687;
  }
  float S[32][4];
#pragma unroll
  for (int nt = 0; nt < 32; ++nt) {
    bf16x8 kb0 = ld_bf8(Kp + (size_t)(nt * 16 + fr) * 64 + fg * 8);
    bf16x8 kb1 = ld_bf8(Kp + (size_t)(nt * 16 + fr) * 64 + 32 + fg * 8);
    f32x4 c = {};
    c = mfma16(qa0, kb0, c);
    c = mfma16(qa1, kb1, c);
    int j = nt * 16 + fr - 1;
    int jj = j < 0 ? 0 : j;
    int Pj = (jj >> 6) * 225 + ((jj >> 3) & 7) * 15 + (jj & 7);
    bool jok = (j >= 0);
#pragma unroll
    for (int r = 0; r < 4; ++r) {
      float bv = Tb[PiA[r] - Pj];
      S[nt][r] = c[r] + ((iok[r] && jok) ? bv : 0.0f);
    }
  }

  // --- softmax over 512 cols (16-lane-group shfl reduce) ---
#pragma unroll
  for (int r = 0; r < 4; ++r) {
    float m = -1e30f;
#pragma unroll
    for (int nt = 0; nt < 32; ++nt) m = fmaxf(m, S[nt][r]);
#pragma unroll
    for (int off = 1; off < 16; off <<= 1) m = fmaxf(m, __shfl_xor(m, off));
    float s = 0.f;
#pragma unroll
    for (int nt = 0; nt < 32; ++nt) { float e = __expf(S[nt][r] - m); S[nt][r] = e; s += e; }
#pragma unroll
    for (int off = 1; off < 16; off <<= 1) s += __shfl_xor(s, off);
    float inv = 1.0f / s;
#pragma unroll
    for (int nt = 0; nt < 32; ++nt) S[nt][r] *= inv;
  }

  // --- PV in two k-halves of 256 ---
  uint16_t* Pw = Ph + w * 4096;
  f32x4 o[4] = {};
#pragma unroll
  for (int hf = 0; hf < 2; ++hf) {
    if (hf == 1) {
      __syncthreads();  // all waves done with half-0 VT/P
#pragma unroll
      for (int it = 0; it < 8; ++it) {
        int d = it * 8 + (tid >> 5);
        int cb = (tid & 31) ^ (d & 7);
        gl_lds16(Vt + (size_t)d * 512 + 256 + cb * 8, VTh + it * 2048 + tid * 8);
      }
    }
    // write P half (XOR-swizzled 16B blocks within 256 cols)
#pragma unroll
    for (int nt = hf * 16; nt < hf * 16 + 16; ++nt) {
      int c = (nt - hf * 16) * 16 + fr;
      int cb = c >> 3, co = c & 7;
#pragma unroll
      for (int r = 0; r < 4; ++r) {
        int row = fg * 4 + r;
        Pw[row * 256 + ((cb ^ (row & 7)) << 3) + co] = f2bf(S[nt][r]);
      }
    }
    __syncthreads();  // VT half + P half visible
#pragma unroll
    for (int ks = 0; ks < 8; ++ks) {
      bf16x8 pa = ld_bf8(Pw + fr * 256 + (((ks * 4 + fg) ^ (fr & 7)) << 3));
#pragma unroll
      for (int n2 = 0; n2 < 4; ++n2) {
        int vrow = n2 * 16 + fr;
        bf16x8 vv = ld_bf8(VTh + vrow * 256 + (((ks * 4 + fg) ^ (vrow & 7)) << 3));
        o[n2] = mfma16(pa, vv, o[n2]);
      }
    }
  }

  // --- write out (B, L, H*64) bf16 ---
#pragma unroll
  for (int n2 = 0; n2 < 4; ++n2)
#pragma unroll
    for (int r = 0; r < 4; ++r) {
      int q = qw + fg * 4 + r;
      int d = n2 * 16 + fr;
      out[(size_t)(b * CL + q) * CD + h * 64 + d] = f2bf(o[n2][r]);
    }
}

// ---------------- LayerNorm over D=1024, one block per row ----------------
__global__ __launch_bounds__(256) void ln_kernel(const float* __restrict__ x,
                                                 const float* __restrict__ gamma,
                                                 const float* __restrict__ beta,
                                                 float* __restrict__ out) {
  const int row = blockIdx.x;
  const int tid = threadIdx.x;
  const float4 v = ((const float4*)(x + (size_t)row * 1024))[tid];
  float s = v.x + v.y + v.z + v.w;
  float ss = v.x * v.x + v.y * v.y + v.z * v.z + v.w * v.w;
#pragma unroll
  for (int off = 1; off < 64; off <<= 1) {
    s += __shfl_xor(s, off);
    ss += __shfl_xor(ss, off);
  }
  __shared__ float ps[4], pss[4];
  const int w = tid >> 6, lane = tid & 63;
  if (lane == 0) { ps[w] = s; pss[w] = ss; }
  __syncthreads();
  s = ps[0] + ps[1] + ps[2] + ps[3];
  ss = pss[0] + pss[1] + pss[2] + pss[3];
  float mu = s * (1.0f / 1024.0f);
  float var = ss * (1.0f / 1024.0f) - mu * mu;
  float rs = rsqrtf(var + 1e-6f);
  const float4 g = ((const float4*)gamma)[tid];
  const float4 be = ((const float4*)beta)[tid];
  float4 o;
  o.x = (v.x - mu) * rs * g.x + be.x;
  o.y = (v.y - mu) * rs * g.y + be.y;
  o.z = (v.z - mu) * rs * g.z + be.z;
  o.w = (v.w - mu) * rs * g.w + be.w;
  ((float4*)(out + (size_t)row * 1024))[tid] = o;
}

extern "C" void kernel_launch(void* const* d_in, const int* in_sizes, int n_in,
                              void* d_out, int out_size, void* d_ws, size_t ws_size,
                              hipStream_t stream) {
  (void)in_sizes; (void)n_in; (void)out_size; (void)ws_size;
  const float* q = (const float*)d_in[0];
  const float* k = (const float*)d_in[1];
  const float* v = (const float*)d_in[2];
  const float* w_q = (const float*)d_in[3];
  const float* w_k = (const float*)d_in[4];
  const float* w_v = (const float*)d_in[5];
  const float* w_fc = (const float*)d_in[6];
  const float* rel_table = (const float*)d_in[7];
  const float* ln_g = (const float*)d_in[9];
  const float* ln_b = (const float*)d_in[10];
  float* out = (float*)d_out;

  uint8_t* ws = (uint8_t*)d_ws;
  size_t off = 0;
  auto carve = [&](size_t bytes) {
    uint8_t* p = ws + off;
    off += (bytes + 255) & ~(size_t)255;
    return p;
  };
  uint16_t* wqt = (uint16_t*)carve((size_t)CD * CD * 2);
  uint16_t* wkt = (uint16_t*)carve((size_t)CD * CD * 2);
  uint16_t* wvt = (uint16_t*)carve((size_t)CD * CD * 2);
  uint16_t* wft = (uint16_t*)carve((size_t)CD * CD * 2);
  uint16_t* qb = (uint16_t*)carve((size_t)CM * CD * 2);  // reused as fc_out (with kb)
  uint16_t* kb = (uint16_t*)carve((size_t)CM * CD * 2);
  uint16_t* vb = (uint16_t*)carve((size_t)CM * CD * 2);  // reused as attn_out
  uint16_t* qhp = (uint16_t*)carve((size_t)CBH * CL * 64 * 2);
  uint16_t* khp = (uint16_t*)carve((size_t)CBH * CL * 64 * 2);
  uint16_t* vhp = (uint16_t*)carve((size_t)CBH * CL * 64 * 2);
  uint16_t* vtp = (uint16_t*)carve((size_t)CBH * 64 * CL * 2);  // V^T heads
  float* rtTp = (float*)carve((size_t)CH * TPAD * 4);
  uint16_t* attn_out = vb;        // vb dead after proj consumes it
  float* fc_out = (float*)qb;     // qb+kb dead after proj (32MB contiguous)

  const int n4 = CM * CD / 4;
  cvt_kernel<<<2048, 256, 0, stream>>>(q, qb, n4);
  cvt_kernel<<<2048, 256, 0, stream>>>(k, kb, n4);
  cvt_kernel<<<2048, 256, 0, stream>>>(v, vb, n4);
  dim3 tb(32, 8);
  wtrans_kernel<<<dim3(32, 32), tb, 0, stream>>>(w_q, wqt);
  wtrans_kernel<<<dim3(32, 32), tb, 0, stream>>>(w_k, wkt);
  wtrans_kernel<<<dim3(32, 32), tb, 0, stream>>>(w_v, wvt);
  wtrans_kernel<<<dim3(32, 32), tb, 0, stream>>>(w_fc, wft);
  ttrans_kernel<<<16, 256, 0, stream>>>(rel_table, rtTp);

  proj_kernel<<<dim3(CD / 128, CM / 128, 3), 256, 0, stream>>>(
      qb, kb, vb, wqt, wkt, wvt, qhp, khp, vhp);

  vtrans_kernel<<<dim3(CBH, 8), 256, 0, stream>>>(vhp, vtp);

  attn_kernel<<<dim3(CL / 64, CBH), 256, 0, stream>>>(qhp, khp, vtp, rtTp, attn_out);

  fc_kernel<<<dim3(CD / 128, CM / 128), 256, 0, stream>>>(attn_out, wft, q, fc_out);

  ln_kernel<<<CM, 256, 0, stream>>>(fc_out, ln_g, ln_b, out);
}

// Round 6
// 374.056 us; speedup vs baseline: 1.9809x; 1.0552x over previous
//
#include <hip/hip_runtime.h>
#include <stdint.h>

#define DEVI __device__ __forceinline__

typedef __bf16 bf16x8 __attribute__((ext_vector_type(8)));
typedef float f32x4 __attribute__((ext_vector_type(4)));

// Problem constants
static constexpr int CB = 16;      // batch
static constexpr int CL = 512;     // seq len
static constexpr int CD = 1024;    // model dim
static constexpr int CH = 16;      // heads
static constexpr int CBH = CB * CH;        // 256
static constexpr int CM = CB * CL;         // 8192 rows
static constexpr int TPAD = 3392;          // rel_table slice padded (3375 -> /16)

DEVI uint16_t f2bf(float f) {
  __bf16 h = (__bf16)f;              // native v_cvt (RNE), m240: compiler handles it
  union { __bf16 h; uint16_t u; } c; c.h = h;
  return c.u;
}

DEVI f32x4 mfma16(bf16x8 a, bf16x8 b, f32x4 c) {
  return __builtin_amdgcn_mfma_f32_16x16x32_bf16(a, b, c, 0, 0, 0);
}

DEVI void gl_lds16(const void* g, void* l) {
  __builtin_amdgcn_global_load_lds(
      (const __attribute__((address_space(1))) void*)g,
      (__attribute__((address_space(3))) void*)l, 16, 0, 0);
}

DEVI bf16x8 ld_bf8(const uint16_t* p) { return *(const bf16x8*)p; }

// ---------------- fp32 -> bf16 cast, 3 tensors in one launch ----------------
__global__ __launch_bounds__(256) void cvt3_kernel(
    const float* __restrict__ q, const float* __restrict__ k, const float* __restrict__ v,
    uint16_t* __restrict__ qb, uint16_t* __restrict__ kb, uint16_t* __restrict__ vb) {
  const int z = blockIdx.y;
  const float* in = (z == 0) ? q : ((z == 1) ? k : v);
  uint16_t* out = (z == 0) ? qb : ((z == 1) ? kb : vb);
  const int n4 = CM * CD / 4;
  int i = blockIdx.x * blockDim.x + threadIdx.x;
  int stride = gridDim.x * blockDim.x;
  for (; i < n4; i += stride) {
    float4 vv = ((const float4*)in)[i];
    ushort4 o;
    o.x = f2bf(vv.x); o.y = f2bf(vv.y); o.z = f2bf(vv.z); o.w = f2bf(vv.w);
    ((ushort4*)out)[i] = o;
  }
}

// ---------------- 1024x1024 transpose + cast (4 weights, one launch) ----------------
__global__ __launch_bounds__(256) void wtrans4_kernel(
    const float* __restrict__ wq, const float* __restrict__ wk,
    const float* __restrict__ wv, const float* __restrict__ wf,
    uint16_t* __restrict__ oq, uint16_t* __restrict__ ok,
    uint16_t* __restrict__ ov, uint16_t* __restrict__ of) {
  __shared__ float tile[32][33];
  const int z = blockIdx.z;
  const float* in = (z == 0) ? wq : ((z == 1) ? wk : ((z == 2) ? wv : wf));
  uint16_t* out = (z == 0) ? oq : ((z == 1) ? ok : ((z == 2) ? ov : of));
  int bx = blockIdx.x * 32, by = blockIdx.y * 32;
  int tx = threadIdx.x, ty = threadIdx.y;  // block (32,8)
#pragma unroll
  for (int i = 0; i < 32; i += 8)
    tile[ty + i][tx] = in[(size_t)(by + ty + i) * 1024 + bx + tx];
  __syncthreads();
#pragma unroll
  for (int i = 0; i < 32; i += 8)
    out[(size_t)(bx + ty + i) * 1024 + by + tx] = f2bf(tile[tx][ty + i]);
}

// ---------------- rel_table (3375,16) -> padded transposed (16, 3392) ----------------
__global__ __launch_bounds__(256) void ttrans_kernel(const float* __restrict__ rt,
                                                     float* __restrict__ rtT) {
  int h = blockIdx.x;
  for (int i = threadIdx.x; i < 3375; i += 256)
    rtT[(size_t)h * TPAD + i] = rt[(size_t)i * 16 + h];
}

// ---------------- V heads (bh,512,64) -> (bh,64,512) bf16 ----------------
__global__ __launch_bounds__(256) void vtrans_kernel(const uint16_t* __restrict__ in,
                                                     uint16_t* __restrict__ out) {
  __shared__ uint t[64][33];
  const int bh = blockIdx.x, l0 = blockIdx.y * 64;
  const int tid = threadIdx.x, tx = tid & 31, ty = tid >> 5;
  const uint* src = (const uint*)(in + ((size_t)bh * 512 + l0) * 64);
#pragma unroll
  for (int i = 0; i < 8; ++i)
    t[ty * 8 + i][tx] = src[(ty * 8 + i) * 32 + tx];
  __syncthreads();
#pragma unroll
  for (int i = 0; i < 8; ++i) {
    int d = ty + i * 8;
    uint w0 = t[tx * 2][d >> 1], w1 = t[tx * 2 + 1][d >> 1];
    uint v0 = (d & 1) ? (w0 >> 16) : (w0 & 0xffffu);
    uint v1 = (d & 1) ? (w1 >> 16) : (w1 & 0xffffu);
    ((uint*)(out + ((size_t)(bh * 64 + d) * 512 + l0)))[tx] = v0 | (v1 << 16);
  }
}

// ---------------- GEMM mainloop: C = A(MxK) * Bt(NxK)^T, 128x128 tile, BK=32 ----------------
DEVI void gemm_core(const uint16_t* __restrict__ A, const uint16_t* __restrict__ Bt,
                    int K, uint16_t* As, uint16_t* Bs, f32x4 (&acc)[4][4]) {
  const int tid = threadIdx.x;
  const int srow = tid >> 2;           // 0..63
  const int scol = (tid & 3) * 8;      // 0,8,16,24
  const uint16_t* Ag = A + (size_t)srow * K + scol;
  const uint16_t* Bg = Bt + (size_t)srow * K + scol;
  uint16_t* Asl = As + srow * 32 + scol;   // byte off = tid*16 (wave base + lane*16)
  uint16_t* Bsl = Bs + srow * 32 + scol;
  const int fr = tid & 15;
  const int fk = ((tid >> 4) & 3) * 8;
  const int w = tid >> 6;
  const int wm = (w >> 1) * 64, wn = (w & 1) * 64;
  for (int k0 = 0; k0 < K; k0 += 32) {
    gl_lds16(Ag + k0, Asl);
    gl_lds16(Ag + (size_t)64 * K + k0, Asl + 64 * 32);
    gl_lds16(Bg + k0, Bsl);
    gl_lds16(Bg + (size_t)64 * K + k0, Bsl + 64 * 32);
    asm volatile("s_waitcnt vmcnt(0)" ::: "memory");
    __syncthreads();
    bf16x8 af[4], bfr[4];
#pragma unroll
    for (int t = 0; t < 4; ++t) af[t] = ld_bf8(As + (wm + t * 16 + fr) * 32 + fk);
#pragma unroll
    for (int t = 0; t < 4; ++t) bfr[t] = ld_bf8(Bs + (wn + t * 16 + fr) * 32 + fk);
#pragma unroll
    for (int mt = 0; mt < 4; ++mt)
#pragma unroll
      for (int nt = 0; nt < 4; ++nt)
        acc[mt][nt] = mfma16(af[mt], bfr[nt], acc[mt][nt]);
    __syncthreads();
  }
}

// ---------------- projection GEMM (z = 0:q, 1:k, 2:v); out (BH, L, 64) bf16 ----------------
__global__ __launch_bounds__(256) void proj_kernel(
    const uint16_t* __restrict__ qb, const uint16_t* __restrict__ kb,
    const uint16_t* __restrict__ vb, const uint16_t* __restrict__ wq,
    const uint16_t* __restrict__ wk, const uint16_t* __restrict__ wv,
    uint16_t* __restrict__ qh, uint16_t* __restrict__ kh, uint16_t* __restrict__ vh) {
  __shared__ uint16_t As[128 * 32], Bs[128 * 32];
  const int z = blockIdx.z;
  const uint16_t* A = (z == 0) ? qb : ((z == 1) ? kb : vb);
  const uint16_t* Bt = (z == 0) ? wq : ((z == 1) ? wk : wv);
  uint16_t* out = (z == 0) ? qh : ((z == 1) ? kh : vh);
  const float scale = (z == 0) ? 0.125f : 1.0f;  // 1/sqrt(DK) on Q only
  const int m0 = blockIdx.y * 128, n0 = blockIdx.x * 128;
  f32x4 acc[4][4] = {};
  gemm_core(A + (size_t)m0 * CD, Bt + (size_t)n0 * CD, CD, As, Bs, acc);
  const int tid = threadIdx.x;
  const int w = tid >> 6, fr = tid & 15, fg = (tid >> 4) & 3;
  const int wm = (w >> 1) * 64, wn = (w & 1) * 64;
#pragma unroll
  for (int mt = 0; mt < 4; ++mt)
#pragma unroll
    for (int nt = 0; nt < 4; ++nt)
#pragma unroll
      for (int r = 0; r < 4; ++r) {
        int gm = m0 + wm + mt * 16 + fg * 4 + r;   // b*512 + l
        int gn = n0 + wn + nt * 16 + fr;           // h*64 + d
        int b = gm >> 9, l = gm & 511, h = gn >> 6, d = gn & 63;
        out[(((size_t)(b * 16 + h) << 9) + l) * 64 + d] = f2bf(acc[mt][nt][r] * scale);
      }
}

// ---------------- FC GEMM + residual; fp32 out ----------------
__global__ __launch_bounds__(256) void fc_kernel(const uint16_t* __restrict__ A,
                                                 const uint16_t* __restrict__ Wt,
                                                 const float* __restrict__ resid,
                                                 float* __restrict__ out) {
  __shared__ uint16_t As[128 * 32], Bs[128 * 32];
  const int m0 = blockIdx.y * 128, n0 = blockIdx.x * 128;
  f32x4 acc[4][4] = {};
  gemm_core(A + (size_t)m0 * CD, Wt + (size_t)n0 * CD, CD, As, Bs, acc);
  const int tid = threadIdx.x;
  const int w = tid >> 6, fr = tid & 15, fg = (tid >> 4) & 3;
  const int wm = (w >> 1) * 64, wn = (w & 1) * 64;
#pragma unroll
  for (int mt = 0; mt < 4; ++mt)
#pragma unroll
    for (int nt = 0; nt < 4; ++nt)
#pragma unroll
      for (int r = 0; r < 4; ++r) {
        int gm = m0 + wm + mt * 16 + fg * 4 + r;
        int gn = n0 + wn + nt * 16 + fr;
        size_t idx = (size_t)gm * CD + gn;
        out[idx] = acc[mt][nt][r] + resid[idx];
      }
}

// ---------------- fused attention: scores + inline rel-bias + softmax + PV ----------------
// grid 2048 linear, XCD-chunked decode; block 256 (4 waves, each wave owns 16 q rows)
// LDS: table slice 13.5KB + VT half 32KB + P half 32KB = 79KB -> 2 WG/CU
__global__ __launch_bounds__(256) void attn_kernel(
    const uint16_t* __restrict__ qh, const uint16_t* __restrict__ kh,
    const uint16_t* __restrict__ vt, const float* __restrict__ rtT,
    uint16_t* __restrict__ out) {
  __shared__ float Tb[TPAD];            // rel_table slice for this head
  __shared__ uint16_t VTh[64 * 256];    // V^T half [d][l'], XOR-swizzled 16B blocks
  __shared__ uint16_t Ph[4 * 16 * 256]; // per-wave P half, XOR-swizzled 16B blocks
  // XCD-aware decode: 8 XCDs x 256 contiguous work items; each XCD owns 2 heads
  // so its L2 reuse set = {K, VT} for 32 bh = ~4MB.
  const int lin = blockIdx.x;
  const int idx = (lin & 7) * 256 + (lin >> 3);
  const int h = idx >> 7;
  const int rem = idx & 127;
  const int b = rem >> 3;
  const int bh = b * 16 + h;
  const int q0 = (rem & 7) * 64;
  const int tid = threadIdx.x, lane = tid & 63, w = tid >> 6;
  const int fr = lane & 15, fg = lane >> 4;
  const size_t base = (size_t)bh * CL * 64;
  const uint16_t* Kp = kh + base;
  const uint16_t* Qp = qh + base;
  const uint16_t* Vt = vt + base;       // (64, 512) layout

  // stage rel_table slice (coalesced float4)
  const float4* rt4 = (const float4*)(rtT + (size_t)h * TPAD);
#pragma unroll
  for (int t = tid; t < TPAD / 4; t += 256) ((float4*)Tb)[t] = rt4[t];

  // issue VT half-0 staging: linear LDS dest, inverse-swizzled global source (rule 21)
#pragma unroll
  for (int it = 0; it < 8; ++it) {
    int d = it * 8 + (tid >> 5);
    int cb = (tid & 31) ^ (d & 7);          // logical 16B col-block for this slot
    gl_lds16(Vt + (size_t)d * 512 + cb * 8, VTh + it * 2048 + tid * 8);
  }
  __syncthreads();  // Tb + VT half-0 ready

  // --- scores S = (Q/8) K^T + rel bias ---
  const int qw = q0 + w * 16;
  bf16x8 qa0 = ld_bf8(Qp + (size_t)(qw + fr) * 64 + fg * 8);
  bf16x8 qa1 = ld_bf8(Qp + (size_t)(qw + fr) * 64 + 32 + fg * 8);
  int PiA[4]; bool iok[4];
#pragma unroll
  for (int r = 0; r < 4; ++r) {
    int i = qw + fg * 4 + r - 1;
    iok[r] = (i >= 0);
    int ii = i < 0 ? 0 : i;
    PiA[r] = (ii >> 6) * 225 + ((ii >> 3) & 7) * 15 + (ii & 7) + 1687;
  }
  float S[32][4];
#pragma unroll
  for (int nt = 0; nt < 32; ++nt) {
    bf16x8 kb0 = ld_bf8(Kp + (size_t)(nt * 16 + fr) * 64 + fg * 8);
    bf16x8 kb1 = ld_bf8(Kp + (size_t)(nt * 16 + fr) * 64 + 32 + fg * 8);
    f32x4 c = {};
    c = mfma16(qa0, kb0, c);
    c = mfma16(qa1, kb1, c);
    int j = nt * 16 + fr - 1;
    int jj = j < 0 ? 0 : j;
    int Pj = (jj >> 6) * 225 + ((jj >> 3) & 7) * 15 + (jj & 7);
    bool jok = (j >= 0);
#pragma unroll
    for (int r = 0; r < 4; ++r) {
      float bv = Tb[PiA[r] - Pj];
      S[nt][r] = c[r] + ((iok[r] && jok) ? bv : 0.0f);
    }
  }

  // --- softmax over 512 cols (16-lane-group shfl reduce); normalization DEFERRED ---
  float invr[4];
#pragma unroll
  for (int r = 0; r < 4; ++r) {
    float m = -1e30f;
#pragma unroll
    for (int nt = 0; nt < 32; ++nt) m = fmaxf(m, S[nt][r]);
#pragma unroll
    for (int off = 1; off < 16; off <<= 1) m = fmaxf(m, __shfl_xor(m, off));
    float s = 0.f;
#pragma unroll
    for (int nt = 0; nt < 32; ++nt) { float e = __expf(S[nt][r] - m); S[nt][r] = e; s += e; }
#pragma unroll
    for (int off = 1; off < 16; off <<= 1) s += __shfl_xor(s, off);
    invr[r] = 1.0f / s;
  }

  // --- PV in two k-halves of 256 (unnormalized P, e <= 1) ---
  uint16_t* Pw = Ph + w * 4096;
  f32x4 o[4] = {};
#pragma unroll
  for (int hf = 0; hf < 2; ++hf) {
    if (hf == 1) {
      __syncthreads();  // all waves done with half-0 VT/P
#pragma unroll
      for (int it = 0; it < 8; ++it) {
        int d = it * 8 + (tid >> 5);
        int cb = (tid & 31) ^ (d & 7);
        gl_lds16(Vt + (size_t)d * 512 + 256 + cb * 8, VTh + it * 2048 + tid * 8);
      }
    }
    // write P half (XOR-swizzled 16B blocks within 256 cols)
#pragma unroll
    for (int nt = hf * 16; nt < hf * 16 + 16; ++nt) {
      int c = (nt - hf * 16) * 16 + fr;
      int cb = c >> 3, co = c & 7;
#pragma unroll
      for (int r = 0; r < 4; ++r) {
        int row = fg * 4 + r;
        Pw[row * 256 + ((cb ^ (row & 7)) << 3) + co] = f2bf(S[nt][r]);
      }
    }
    __syncthreads();  // VT half + P half visible
#pragma unroll
    for (int ks = 0; ks < 8; ++ks) {
      bf16x8 pa = ld_bf8(Pw + fr * 256 + (((ks * 4 + fg) ^ (fr & 7)) << 3));
#pragma unroll
      for (int n2 = 0; n2 < 4; ++n2) {
        int vrow = n2 * 16 + fr;
        bf16x8 vv = ld_bf8(VTh + vrow * 256 + (((ks * 4 + fg) ^ (vrow & 7)) << 3));
        o[n2] = mfma16(pa, vv, o[n2]);
      }
    }
  }

  // --- write out (B, L, H*64) bf16, normalize here ---
#pragma unroll
  for (int n2 = 0; n2 < 4; ++n2)
#pragma unroll
    for (int r = 0; r < 4; ++r) {
      int q = qw + fg * 4 + r;
      int d = n2 * 16 + fr;
      out[(size_t)(b * CL + q) * CD + h * 64 + d] = f2bf(o[n2][r] * invr[r]);
    }
}

// ---------------- LayerNorm over D=1024, one block per row ----------------
__global__ __launch_bounds__(256) void ln_kernel(const float* __restrict__ x,
                                                 const float* __restrict__ gamma,
                                                 const float* __restrict__ beta,
                                                 float* __restrict__ out) {
  const int row = blockIdx.x;
  const int tid = threadIdx.x;
  const float4 v = ((const float4*)(x + (size_t)row * 1024))[tid];
  float s = v.x + v.y + v.z + v.w;
  float ss = v.x * v.x + v.y * v.y + v.z * v.z + v.w * v.w;
#pragma unroll
  for (int off = 1; off < 64; off <<= 1) {
    s += __shfl_xor(s, off);
    ss += __shfl_xor(ss, off);
  }
  __shared__ float ps[4], pss[4];
  const int w = tid >> 6, lane = tid & 63;
  if (lane == 0) { ps[w] = s; pss[w] = ss; }
  __syncthreads();
  s = ps[0] + ps[1] + ps[2] + ps[3];
  ss = pss[0] + pss[1] + pss[2] + pss[3];
  float mu = s * (1.0f / 1024.0f);
  float var = ss * (1.0f / 1024.0f) - mu * mu;
  float rs = rsqrtf(var + 1e-6f);
  const float4 g = ((const float4*)gamma)[tid];
  const float4 be = ((const float4*)beta)[tid];
  float4 o;
  o.x = (v.x - mu) * rs * g.x + be.x;
  o.y = (v.y - mu) * rs * g.y + be.y;
  o.z = (v.z - mu) * rs * g.z + be.z;
  o.w = (v.w - mu) * rs * g.w + be.w;
  ((float4*)(out + (size_t)row * 1024))[tid] = o;
}

extern "C" void kernel_launch(void* const* d_in, const int* in_sizes, int n_in,
                              void* d_out, int out_size, void* d_ws, size_t ws_size,
                              hipStream_t stream) {
  (void)in_sizes; (void)n_in; (void)out_size; (void)ws_size;
  const float* q = (const float*)d_in[0];
  const float* k = (const float*)d_in[1];
  const float* v = (const float*)d_in[2];
  const float* w_q = (const float*)d_in[3];
  const float* w_k = (const float*)d_in[4];
  const float* w_v = (const float*)d_in[5];
  const float* w_fc = (const float*)d_in[6];
  const float* rel_table = (const float*)d_in[7];
  const float* ln_g = (const float*)d_in[9];
  const float* ln_b = (const float*)d_in[10];
  float* out = (float*)d_out;

  uint8_t* ws = (uint8_t*)d_ws;
  size_t off = 0;
  auto carve = [&](size_t bytes) {
    uint8_t* p = ws + off;
    off += (bytes + 255) & ~(size_t)255;
    return p;
  };
  uint16_t* wqt = (uint16_t*)carve((size_t)CD * CD * 2);
  uint16_t* wkt = (uint16_t*)carve((size_t)CD * CD * 2);
  uint16_t* wvt = (uint16_t*)carve((size_t)CD * CD * 2);
  uint16_t* wft = (uint16_t*)carve((size_t)CD * CD * 2);
  uint16_t* qb = (uint16_t*)carve((size_t)CM * CD * 2);  // reused as fc_out (with kb)
  uint16_t* kb = (uint16_t*)carve((size_t)CM * CD * 2);
  uint16_t* vb = (uint16_t*)carve((size_t)CM * CD * 2);  // reused as attn_out
  uint16_t* qhp = (uint16_t*)carve((size_t)CBH * CL * 64 * 2);
  uint16_t* khp = (uint16_t*)carve((size_t)CBH * CL * 64 * 2);
  uint16_t* vhp = (uint16_t*)carve((size_t)CBH * CL * 64 * 2);
  uint16_t* vtp = (uint16_t*)carve((size_t)CBH * 64 * CL * 2);  // V^T heads
  float* rtTp = (float*)carve((size_t)CH * TPAD * 4);
  uint16_t* attn_out = vb;        // vb dead after proj consumes it
  float* fc_out = (float*)qb;     // qb+kb dead after proj (32MB contiguous)

  cvt3_kernel<<<dim3(1024, 3), 256, 0, stream>>>(q, k, v, qb, kb, vb);
  wtrans4_kernel<<<dim3(32, 32, 4), dim3(32, 8), 0, stream>>>(
      w_q, w_k, w_v, w_fc, wqt, wkt, wvt, wft);
  ttrans_kernel<<<16, 256, 0, stream>>>(rel_table, rtTp);

  proj_kernel<<<dim3(CD / 128, CM / 128, 3), 256, 0, stream>>>(
      qb, kb, vb, wqt, wkt, wvt, qhp, khp, vhp);

  vtrans_kernel<<<dim3(CBH, 8), 256, 0, stream>>>(vhp, vtp);

  attn_kernel<<<2048, 256, 0, stream>>>(qhp, khp, vtp, rtTp, attn_out);

  fc_kernel<<<dim3(CD / 128, CM / 128), 256, 0, stream>>>(attn_out, wft, q, fc_out);

  ln_kernel<<<CM, 256, 0, stream>>>(fc_out, ln_g, ln_b, out);
}